// Round 2
// baseline (153.149 us; speedup 1.0000x reference)
//
#include <hip/hip_runtime.h>

#define MSAMP 1535
#define CHUNKS 6

// ---- kernel 1: per-sample interpolation + alpha + sigmoid(rgb_raw) ----
__global__ __launch_bounds__(256) void k_p1(const float* __restrict__ ro,
                                            const float* __restrict__ rd,
                                            const float* __restrict__ gridf,
                                            const float* __restrict__ atomsf,
                                            float* __restrict__ alpha_out,
                                            float4* __restrict__ sig_ws) {
    const float RAD = 1.3f;
    const float STEPF = (float)(1.3 * 2.0 / 32.0 / 8.0 / 2.0);
    int ray = blockIdx.x / CHUNKS;
    int m = (blockIdx.x % CHUNKS) * 256 + (int)threadIdx.x;

    float ox = ro[ray * 3 + 0], oy = ro[ray * 3 + 1], oz = ro[ray * 3 + 2];
    float dx = rd[ray * 3 + 0], dy = rd[ray * 3 + 1], dz = rd[ray * 3 + 2];

    float a0 = ( RAD - ox) / dx, b0 = (-RAD - ox) / dx;
    float a1 = ( RAD - oy) / dy, b1 = (-RAD - oy) / dy;
    float a2 = ( RAD - oz) / dz, b2 = (-RAD - oz) / dz;
    float st = fmaxf(fmaxf(fminf(a0, b0), fminf(a1, b1)), fminf(a2, b2));

    if (m >= MSAMP) return;
    float t = st + (float)m * STEPF;
    float px = ox + t * dx, py = oy + t * dy, pz = oz + t * dz;
    int idx = ray * MSAMP + m;
    bool inb = (px > -RAD) && (px < RAD) && (py > -RAD) && (py < RAD) && (pz > -RAD) && (pz < RAD);
    if (!inb) { alpha_out[idx] = 0.0f; return; }

    // normalized coords
    const float inv2R = 1.0f / 2.6f;
    float pnx = fminf(fmaxf((px + RAD) * inv2R, 0.0f), 0.999999f);
    float pny = fminf(fmaxf((py + RAD) * inv2R, 0.0f), 0.999999f);
    float pnz = fminf(fmaxf((pz + RAD) * inv2R, 0.0f), 0.999999f);

    float cpx = pnx * 32.0f, cpy = pny * 32.0f, cpz = pnz * 32.0f;
    float cfx = floorf(cpx), cfy = floorf(cpy), cfz = floorf(cpz);
    int cix = (int)cfx, ciy = (int)cfy, ciz = (int)cfz;

    float fpx = (cpx - cfx) * 8.0f - 0.5f;
    float fpy = (cpy - cfy) * 8.0f - 0.5f;
    float fpz = (cpz - cfz) * 8.0f - 0.5f;
    float ffx = floorf(fpx), ffy = floorf(fpy), ffz = floorf(fpz);
    int f0x = (int)ffx, f0y = (int)ffy, f0z = (int)ffz;
    float wx = fpx - ffx, wy = fpy - ffy, wz = fpz - ffz;

    int ixa[2] = { max(f0x, 0), min(f0x + 1, 7) };
    int iya[2] = { max(f0y, 0), min(f0y + 1, 7) };
    int iza[2] = { max(f0z, 0), min(f0z + 1, 7) };
    float wxa[2] = { 1.0f - wx, wx };
    float wya[2] = { 1.0f - wy, wy };
    float wza[2] = { 1.0f - wz, wz };

    const float* cp = gridf + (((cix * 32 + ciy) * 32 + ciz) << 4);
    float coeff[16];
    {
        float4 c0 = ((const float4*)cp)[0];
        float4 c1 = ((const float4*)cp)[1];
        float4 c2 = ((const float4*)cp)[2];
        float4 c3 = ((const float4*)cp)[3];
        coeff[0]=c0.x; coeff[1]=c0.y; coeff[2]=c0.z; coeff[3]=c0.w;
        coeff[4]=c1.x; coeff[5]=c1.y; coeff[6]=c1.z; coeff[7]=c1.w;
        coeff[8]=c2.x; coeff[9]=c2.y; coeff[10]=c2.z; coeff[11]=c2.w;
        coeff[12]=c3.x; coeff[13]=c3.y; coeff[14]=c3.z; coeff[15]=c3.w;
    }

    float acc[28];
#pragma unroll
    for (int i = 0; i < 28; i++) acc[i] = 0.0f;

#pragma unroll
    for (int cx = 0; cx < 2; cx++)
#pragma unroll
    for (int cy = 0; cy < 2; cy++)
#pragma unroll
    for (int cz = 0; cz < 2; cz++) {
        float wt = wxa[cx] * wya[cy] * wza[cz];
        const float* cell = atomsf + ((ixa[cx] * 8 + iya[cy]) * 8 + iza[cz]) * 448;
#pragma unroll
        for (int a = 0; a < 16; a++) {
            float ca = wt * coeff[a];
            const float4* row = (const float4*)(cell + a * 28);
#pragma unroll
            for (int v = 0; v < 7; v++) {
                float4 q = row[v];
                acc[v * 4 + 0] = fmaf(ca, q.x, acc[v * 4 + 0]);
                acc[v * 4 + 1] = fmaf(ca, q.y, acc[v * 4 + 1]);
                acc[v * 4 + 2] = fmaf(ca, q.z, acc[v * 4 + 2]);
                acc[v * 4 + 3] = fmaf(ca, q.w, acc[v * 4 + 3]);
            }
        }
    }

    float nrm = sqrtf(dx * dx + dy * dy + dz * dz);
    float sigma = fmaxf(acc[27], 0.0f);
    float alpha = 1.0f - expf(-sigma * STEPF * nrm);
    alpha_out[idx] = alpha;

    // SH encode of ray direction, dot with the 3x9 sh coeffs, sigmoid
    float shm[9];
    shm[0] = 0.28209479177387814f;
    shm[1] = -0.4886025119029199f * dy;
    shm[2] =  0.4886025119029199f * dz;
    shm[3] = -0.4886025119029199f * dx;
    shm[4] =  1.0925484305920792f * dx * dy;
    shm[5] = -1.0925484305920792f * dy * dz;
    shm[6] =  0.31539156525252005f * (2.0f * dz * dz - dx * dx - dy * dy);
    shm[7] = -1.0925484305920792f * dx * dz;
    shm[8] =  0.5462742152960396f * (dx * dx - dy * dy);

    float rgb[3];
#pragma unroll
    for (int k = 0; k < 3; k++) {
        float s = 0.0f;
#pragma unroll
        for (int j = 0; j < 9; j++) s = fmaf(shm[j], acc[k * 9 + j], s);
        rgb[k] = 1.0f / (1.0f + expf(-s));
    }
    sig_ws[idx] = make_float4(rgb[0], rgb[1], rgb[2], alpha);
}

// ---- kernel 2: per-ray transmittance scan + reductions ----
__global__ __launch_bounds__(256) void k_p2(const float* __restrict__ ro,
                                            const float* __restrict__ rd,
                                            const float* __restrict__ alpha_in,
                                            const float4* __restrict__ sig_ws,
                                            float* __restrict__ rgb_out,
                                            float* __restrict__ depth_out) {
    const float RAD = 1.3f;
    const float STEPF = (float)(1.3 * 2.0 / 32.0 / 8.0 / 2.0);
    int ray = blockIdx.x;
    int t = threadIdx.x;

    float ox = ro[ray * 3 + 0], oy = ro[ray * 3 + 1], oz = ro[ray * 3 + 2];
    float dx = rd[ray * 3 + 0], dy = rd[ray * 3 + 1], dz = rd[ray * 3 + 2];
    float a0 = ( RAD - ox) / dx, b0 = (-RAD - ox) / dx;
    float a1 = ( RAD - oy) / dy, b1 = (-RAD - oy) / dy;
    float a2 = ( RAD - oz) / dz, b2 = (-RAD - oz) / dz;
    float st = fmaxf(fmaxf(fminf(a0, b0), fminf(a1, b1)), fminf(a2, b2));

    int base = ray * MSAMP;
    float av[6];
#pragma unroll
    for (int k = 0; k < 6; k++) {
        int m = t * 6 + k;
        av[k] = (m < MSAMP) ? alpha_in[base + m] : 0.0f;
    }
    float p = 1.0f;
#pragma unroll
    for (int k = 0; k < 6; k++) p *= (1.0f - av[k] + 1e-10f);

    __shared__ float sp[256];
    sp[t] = p;
    __syncthreads();
    for (int off = 1; off < 256; off <<= 1) {
        float self = sp[t];
        float other = (t >= off) ? sp[t - off] : 1.0f;
        __syncthreads();
        sp[t] = self * other;
        __syncthreads();
    }
    float trans = (t == 0) ? 1.0f : sp[t - 1];
    __syncthreads();

    float ra = 0.0f, ga = 0.0f, ba = 0.0f, da = 0.0f, wsum = 0.0f;
#pragma unroll
    for (int k = 0; k < 6; k++) {
        int m = t * 6 + k;
        if (m < MSAMP) {
            float al = av[k];
            float w = al * trans;
            float4 s = sig_ws[base + m];
            ra = fmaf(w, s.x, ra);
            ga = fmaf(w, s.y, ga);
            ba = fmaf(w, s.z, ba);
            da = fmaf(w, st + (float)m * STEPF, da);
            wsum += w;
            trans *= (1.0f - al + 1e-10f);
        }
    }

    // block reductions (reuse sp)
    float vals[5] = { ra, ga, ba, da, wsum };
    float res[5];
#pragma unroll
    for (int i = 0; i < 5; i++) {
        sp[t] = vals[i];
        __syncthreads();
        for (int off = 128; off > 0; off >>= 1) {
            if (t < off) sp[t] += sp[t + off];
            __syncthreads();
        }
        res[i] = sp[0];
        __syncthreads();
    }
    if (t == 0) {
        float omw = 1.0f - res[4];
        rgb_out[ray * 3 + 0] = res[0] + omw;
        rgb_out[ray * 3 + 1] = res[1] + omw;
        rgb_out[ray * 3 + 2] = res[2] + omw;
        depth_out[ray] = res[3];
    }
}

extern "C" void kernel_launch(void* const* d_in, const int* in_sizes, int n_in,
                              void* d_out, int out_size, void* d_ws, size_t ws_size,
                              hipStream_t stream) {
    const float* ro    = (const float*)d_in[0];
    const float* rd    = (const float*)d_in[1];
    const float* grid  = (const float*)d_in[2];
    const float* atoms = (const float*)d_in[3];
    int B = in_sizes[0] / 3;  // 128

    float4* sig = (float4*)d_ws;

    float* out       = (float*)d_out;
    float* rgb_out   = out;
    float* alpha_out = out + B * 3;
    float* depth_out = out + B * 3 + B * MSAMP;

    hipLaunchKernelGGL(k_p1, dim3(B * CHUNKS), dim3(256), 0, stream,
                       ro, rd, grid, atoms, alpha_out, sig);
    hipLaunchKernelGGL(k_p2, dim3(B), dim3(256), 0, stream,
                       ro, rd, alpha_out, sig, rgb_out, depth_out);
}